// Round 1
// baseline (135.954 us; speedup 1.0000x reference)
//
#include <hip/hip_runtime.h>

// Problem: B=32, C=16, RES=128, N_ANGLES=64
// out[b,0,a,i] = bias + sum_j bilinear(y[b], ys(i,j), xs(i,j))
// where y[b] = sum_c w[c] * x[b,c]   (conv is linear -> fuse before radon)

#define B_   32
#define C_   16
#define RES  128
#define NA   64
#define S_   129   // LDS row stride (pad +1: breaks bank aliasing when x0 uniform across lanes)

// ---------------- Kernel 1: channel reduce (HBM-bound) ----------------
__global__ __launch_bounds__(256) void chan_reduce(const float* __restrict__ x,
                                                   const float* __restrict__ w,
                                                   float* __restrict__ y) {
    int t  = blockIdx.x * 256 + threadIdx.x;   // 131072 threads, one float4 each
    int b  = t >> 12;                          // 4096 float4 per batch image
    int r4 = t & 4095;
    const float4* xb = (const float4*)(x + (size_t)b * C_ * RES * RES);
    float4 acc = make_float4(0.f, 0.f, 0.f, 0.f);
#pragma unroll
    for (int c = 0; c < C_; ++c) {
        float4 v = xb[c * (RES * RES / 4) + r4];
        float wc = w[c];
        acc.x = fmaf(wc, v.x, acc.x);
        acc.y = fmaf(wc, v.y, acc.y);
        acc.z = fmaf(wc, v.z, acc.z);
        acc.w = fmaf(wc, v.w, acc.w);
    }
    ((float4*)y)[(size_t)b * (RES * RES / 4) + r4] = acc;
}

// ---------------- Kernel 2: radon from LDS-resident image ----------------
// grid = 32 batches x 16 angle-groups; block = 512 threads
// thread t: angle = grp*4 + (t>>7), detector row i = t&127; serial sum over j.
__global__ __launch_bounds__(512) void radon_k(const float* __restrict__ y,
                                               const float* __restrict__ angles,
                                               const float* __restrict__ bias,
                                               float* __restrict__ out) {
    __shared__ float lds[RES * S_];   // 66048 B -> 2 blocks/CU
    const int bid = blockIdx.x;
    const int b   = bid >> 4;
    const int grp = bid & 15;
    const int t   = threadIdx.x;

    // ---- stage y[b] (64 KB) into LDS; 8 passes of 16 rows ----
    {
        const float* yb = y + (size_t)b * RES * RES;
        int row0 = t >> 5;          // 0..15
        int col  = (t & 31) * 4;    // 0..124
#pragma unroll
        for (int p = 0; p < 8; ++p) {
            int row = p * 16 + row0;
            float4 v = *(const float4*)(yb + row * RES + col);
            float* d = &lds[row * S_ + col];
            d[0] = v.x; d[1] = v.y; d[2] = v.z; d[3] = v.w;
        }
    }
    __syncthreads();

    const int a = grp * 4 + (t >> 7);   // wave-uniform
    const int i = t & 127;
    float theta = angles[a];
    float sth, cth;
    sincosf(theta, &sth, &cth);

    const float ci = (float)i - 63.5f;
    const float Xi = fmaf(ci, cth, 63.5f);   // xs = ci*c - cj*s + 63.5
    const float Yi = fmaf(ci, sth, 63.5f);   // ys = ci*s + cj*c + 63.5

    float acc = 0.0f;
#pragma unroll 4
    for (int j = 0; j < RES; ++j) {
        float cj = (float)j - 63.5f;
        float X  = fmaf(cj, -sth, Xi);
        float Y  = fmaf(cj,  cth, Yi);
        float fx = floorf(X), fy = floorf(Y);
        float wx = X - fx,    wy = Y - fy;
        int x0 = (int)fx, y0 = (int)fy;     // fx integral -> exact
        int x1 = x0 + 1,  y1 = y0 + 1;
        // validity folded into the 1-D weights: corner (k,l) weight = a_k*b_l,
        // zero iff either axis OOB -> matches reference valid*clip semantics
        float b0 = ((unsigned)x0 < 128u) ? (1.0f - wx) : 0.0f;
        float b1 = ((unsigned)x1 < 128u) ? wx          : 0.0f;
        float a0 = ((unsigned)y0 < 128u) ? (1.0f - wy) : 0.0f;
        float a1 = ((unsigned)y1 < 128u) ? wy          : 0.0f;
        int x0c = min(max(x0, 0), 127), x1c = min(max(x1, 0), 127);
        int y0c = min(max(y0, 0), 127), y1c = min(max(y1, 0), 127);
        const float* r0 = &lds[y0c * S_];
        const float* r1 = &lds[y1c * S_];
        float v00 = r0[x0c], v01 = r0[x1c];
        float v10 = r1[x0c], v11 = r1[x1c];
        acc += a0 * fmaf(b1, v01, b0 * v00) + a1 * fmaf(b1, v11, b0 * v10);
    }

    out[b * (NA * RES) + a * RES + i] = acc + bias[0];
}

extern "C" void kernel_launch(void* const* d_in, const int* in_sizes, int n_in,
                              void* d_out, int out_size, void* d_ws, size_t ws_size,
                              hipStream_t stream) {
    const float* x      = (const float*)d_in[0];   // 32*16*128*128
    const float* angles = (const float*)d_in[1];   // 64
    const float* w      = (const float*)d_in[2];   // 16 (conv_w[0,:,0,0])
    const float* bias   = (const float*)d_in[3];   // 1
    float* out = (float*)d_out;                    // 32*1*64*128 fp32
    float* y   = (float*)d_ws;                     // 32*128*128 fp32 = 2 MiB scratch

    chan_reduce<<<dim3(512), dim3(256), 0, stream>>>(x, w, y);
    radon_k<<<dim3(B_ * 16), dim3(512), 0, stream>>>(y, angles, bias, out);
}

// Round 2
// 106.570 us; speedup vs baseline: 1.2757x; 1.2757x over previous
//
#include <hip/hip_runtime.h>

// B=32, C=16, RES=128, NA=64
// out[b,0,a,i] = bias + sum_j bilinear(y[b], ...), y[b] = sum_c w[c]*x[b,c]
//
// Radon image lives in LDS with a 2-pixel ZERO guard band on all sides:
//   lds rows/cols 0,1 and 130,131 are zero; image[r][c] at lds[r+2][c+2].
// This makes every OOB tap read an actual 0.0 (matches reference
// valid*clip semantics) -> no cmps/cndmasks/int-clamps in the inner loop.
// Row stride 133 (odd) -> vertical lane patterns are bank-conflict-free.

#define B_   32
#define C_   16
#define RES  128
#define NA   64
#define SLDS 133            // LDS row stride in dwords
#define ROWS 132
#define LDSZ (ROWS * SLDS)  // 17556 dwords = 70224 B -> 2 blocks/CU

// ---------------- Kernel 1: channel reduce (HBM-bound) ----------------
__global__ __launch_bounds__(256) void chan_reduce(const float* __restrict__ x,
                                                   const float* __restrict__ w,
                                                   float* __restrict__ y) {
    int t  = blockIdx.x * 256 + threadIdx.x;
    int b  = t >> 12;
    int r4 = t & 4095;
    const float4* xb = (const float4*)(x + (size_t)b * C_ * RES * RES);
    float wr[C_];
#pragma unroll
    for (int c = 0; c < C_; ++c) wr[c] = w[c];
    float4 acc = make_float4(0.f, 0.f, 0.f, 0.f);
#pragma unroll
    for (int c = 0; c < C_; ++c) {
        float4 v = xb[c * (RES * RES / 4) + r4];
        acc.x = fmaf(wr[c], v.x, acc.x);
        acc.y = fmaf(wr[c], v.y, acc.y);
        acc.z = fmaf(wr[c], v.z, acc.z);
        acc.w = fmaf(wr[c], v.w, acc.w);
    }
    ((float4*)y)[(size_t)b * (RES * RES / 4) + r4] = acc;
}

// ---------------- Kernel 2: radon from LDS-resident guarded image ----------------
// grid = 32 batches x 16 angle-groups, block = 512 threads
// thread t: angle = grp*4 + (t>>7) (wave-uniform), detector i = t&127
__global__ __launch_bounds__(512) void radon_k(const float* __restrict__ y,
                                               const float* __restrict__ angles,
                                               const float* __restrict__ bias,
                                               float* __restrict__ out) {
    __shared__ float lds[LDSZ];
    const int bid = blockIdx.x;
    const int b   = bid >> 4;
    const int grp = bid & 15;
    const int t   = threadIdx.x;

    // ---- zero the whole tile (guard band included) ----
    {
        float2* l2 = (float2*)lds;
#pragma unroll
        for (int p = 0; p < 18; ++p) {          // 18*512 >= 8778
            int idx = p * 512 + t;
            if (idx < LDSZ / 2) l2[idx] = make_float2(0.f, 0.f);
        }
        if (t == 0) lds[LDSZ - 1] = 0.f;        // odd tail dword
    }
    __syncthreads();

    // ---- stage image into interior [2..129][2..129] ----
    {
        const float* yb = y + (size_t)b * RES * RES;
#pragma unroll
        for (int p = 0; p < 8; ++p) {           // 4096 float4 total
            int q = p * 512 + t;
            int r = q >> 5;
            int c = (q & 31) << 2;
            float4 v = *(const float4*)(yb + r * RES + c);
            float* d = &lds[(r + 2) * SLDS + (c + 2)];
            d[0] = v.x; d[1] = v.y; d[2] = v.z; d[3] = v.w;
        }
    }
    __syncthreads();

    const int a = grp * 4 + (t >> 7);           // wave-uniform angle
    const int i = t & 127;
    float th = angles[a];
    float s, c;
    __sincosf(th, &s, &c);

    const float ci = (float)i - 63.5f;
    // +63.5 sample center, +2 guard-band offset
    const float Xi = fmaf(ci, c, 65.5f);
    const float Yi = fmaf(ci, s, 65.5f);

    float acc = 0.0f;
#pragma unroll 8
    for (int j = 0; j < RES; ++j) {
        float cj = (float)j - 63.5f;
        float X  = fmaf(cj, -s, Xi);
        float Y  = fmaf(cj,  c, Yi);
        float fx = floorf(X), fy = floorf(Y);
        float wx = X - fx,    wy = Y - fy;
        // clamp to guard band: OOB taps land on zeros -> weights need no masks
        float gx = fminf(fmaxf(fx, 0.0f), 130.0f);   // v_med3_f32
        float gy = fminf(fmaxf(fy, 0.0f), 130.0f);
        int addr = (int)fmaf(gy, (float)SLDS, gx);   // exact (< 2^24)
        const float* p0 = &lds[addr];
        float v00 = p0[0],    v01 = p0[1];           // ds_read2_b32 off 0,1
        float v10 = p0[SLDS], v11 = p0[SLDS + 1];    // ds_read2_b32 off 133,134
        float h0 = fmaf(wx, v01 - v00, v00);
        float h1 = fmaf(wx, v11 - v10, v10);
        acc = acc + fmaf(wy, h1 - h0, h0);
    }

    out[b * (NA * RES) + a * RES + i] = acc + bias[0];
}

extern "C" void kernel_launch(void* const* d_in, const int* in_sizes, int n_in,
                              void* d_out, int out_size, void* d_ws, size_t ws_size,
                              hipStream_t stream) {
    const float* x      = (const float*)d_in[0];   // 32*16*128*128
    const float* angles = (const float*)d_in[1];   // 64
    const float* w      = (const float*)d_in[2];   // 16
    const float* bias   = (const float*)d_in[3];   // 1
    float* out = (float*)d_out;                    // 32*64*128 fp32
    float* y   = (float*)d_ws;                     // 2 MiB scratch

    chan_reduce<<<dim3(512), dim3(256), 0, stream>>>(x, w, y);
    radon_k<<<dim3(B_ * 16), dim3(512), 0, stream>>>(y, angles, bias, out);
}

// Round 4
// 101.834 us; speedup vs baseline: 1.3351x; 1.0465x over previous
//
#include <hip/hip_runtime.h>

// B=32, C=16, RES=128, NA=64
// out[b,0,a,i] = bias + sum_j bilinear(y[b],...), y[b] = sum_c w[c]*x[b,c]
//
// LDS layout: guarded image (2-px zero border) stored as DUPLICATED fp16
// column pairs: P[r][c] = (G[r][c], G[r][c+1]) as half2 (4 B).
// -> all 4 bilinear taps of one sample = ONE ds_read2_b32 (offsets 0, 133).
// Interp = two v_dot2_f32_f16 with packed fp16 corner weights.
// 132 rows x stride 133 x 4 B = 70224 B -> 2 blocks/CU. Odd stride spreads banks.

#define B_   32
#define C_   16
#define RES  128
#define NA   64
#define SLDS 133            // row stride in half2 units (= dwords)
#define ROWS 132
#define LDSZ (ROWS * SLDS)  // 17556 half2 elements (70224 B)

typedef _Float16 half2v __attribute__((ext_vector_type(2)));

// ---------------- Kernel 1: channel reduce (HBM-bound) ----------------
__global__ __launch_bounds__(256) void chan_reduce(const float* __restrict__ x,
                                                   const float* __restrict__ w,
                                                   float* __restrict__ y) {
    int t  = blockIdx.x * 256 + threadIdx.x;
    int b  = t >> 12;
    int r4 = t & 4095;
    const float4* xb = (const float4*)(x + (size_t)b * C_ * RES * RES);
    float wr[C_];
#pragma unroll
    for (int c = 0; c < C_; ++c) wr[c] = w[c];
    float4 acc = make_float4(0.f, 0.f, 0.f, 0.f);
#pragma unroll
    for (int c = 0; c < C_; ++c) {
        float4 v = xb[c * (RES * RES / 4) + r4];
        acc.x = fmaf(wr[c], v.x, acc.x);
        acc.y = fmaf(wr[c], v.y, acc.y);
        acc.z = fmaf(wr[c], v.z, acc.z);
        acc.w = fmaf(wr[c], v.w, acc.w);
    }
    ((float4*)y)[(size_t)b * (RES * RES / 4) + r4] = acc;
}

// ---------------- Kernel 2: radon from LDS fp16 pair-packed image ----------------
// grid = 32 batches x 16 angle-groups, block = 512 threads
__global__ __launch_bounds__(512) void radon_k(const float* __restrict__ y,
                                               const float* __restrict__ angles,
                                               const float* __restrict__ bias,
                                               float* __restrict__ out) {
    __shared__ half2v lds[LDSZ];
    const int bid = blockIdx.x;
    const int b   = bid >> 4;
    const int grp = bid & 15;
    const int t   = threadIdx.x;

    // ---- zero whole tile (guard band included); LDSZ*4B = 8778 float2 ----
    {
        float2* l2 = (float2*)lds;
#pragma unroll
        for (int p = 0; p < 18; ++p) {
            int idx = p * 512 + t;
            if (idx < LDSZ / 2) l2[idx] = make_float2(0.f, 0.f);
        }
    }
    __syncthreads();

    // ---- stage image as duplicated fp16 pairs into interior ----
    // pixel m lives at guard col m+2; P[r][c] = (G[r][c], G[r][c+1])
    {
        const float* yb = y + (size_t)b * RES * RES;
#pragma unroll
        for (int p = 0; p < 8; ++p) {
            int q = p * 512 + t;            // 4096 float4 tiles
            int r = q >> 5;                 // image row
            int k = q & 31;                 // float4 index in row
            float4 v = *(const float4*)(yb + r * RES + (k << 2));
            float v4 = (k < 31) ? yb[r * RES + (k << 2) + 4] : 0.f;
            half2v* row = &lds[(r + 2) * SLDS];
            int c0 = (k << 2) + 2;
            row[c0]     = half2v{(_Float16)v.x, (_Float16)v.y};
            row[c0 + 1] = half2v{(_Float16)v.y, (_Float16)v.z};
            row[c0 + 2] = half2v{(_Float16)v.z, (_Float16)v.w};
            row[c0 + 3] = half2v{(_Float16)v.w, (_Float16)v4};
            if (k == 0) row[1] = half2v{(_Float16)0.f, (_Float16)v.x};
        }
    }
    __syncthreads();

    const int a = grp * 4 + (t >> 7);       // wave-uniform angle
    const int i = t & 127;
    float th = angles[a];
    float s, c;
    __sincosf(th, &s, &c);

    const float ci = (float)i - 63.5f;
    const float Xi = fmaf(ci, c, 65.5f);    // +63.5 center, +2 guard offset
    const float Yi = fmaf(ci, s, 65.5f);

    float acc0 = 0.0f, acc1 = 0.0f;
#pragma unroll 16
    for (int j = 0; j < RES; ++j) {
        float cj = (float)j - 63.5f;
        float X  = fmaf(cj, -s, Xi);
        float Y  = fmaf(cj,  c, Yi);
        float fx = floorf(X), fy = floorf(Y);
        float wx = X - fx,    wy = Y - fy;
        float gx = fminf(fmaxf(fx, 0.0f), 130.0f);   // v_med3_f32
        float gy = fminf(fmaxf(fy, 0.0f), 130.0f);
        int addr = (int)fmaf(gy, (float)SLDS, gx);   // exact (< 2^24)
        half2v p0 = lds[addr];                       // (v00, v01)
        half2v p1 = lds[addr + SLDS];                // (v10, v11) — ds_read2_b32
        float u  = 1.0f - wx;
        float A0 = 1.0f - wy;
        half2v wa = __builtin_bit_cast(half2v, __builtin_amdgcn_cvt_pkrtz(A0 * u, A0 * wx));
        half2v wb = __builtin_bit_cast(half2v, __builtin_amdgcn_cvt_pkrtz(wy * u, wy * wx));
        acc0 = __builtin_amdgcn_fdot2(p0, wa, acc0, false);
        acc1 = __builtin_amdgcn_fdot2(p1, wb, acc1, false);
    }

    out[b * (NA * RES) + a * RES + i] = (acc0 + acc1) + bias[0];
}

extern "C" void kernel_launch(void* const* d_in, const int* in_sizes, int n_in,
                              void* d_out, int out_size, void* d_ws, size_t ws_size,
                              hipStream_t stream) {
    const float* x      = (const float*)d_in[0];   // 32*16*128*128
    const float* angles = (const float*)d_in[1];   // 64
    const float* w      = (const float*)d_in[2];   // 16
    const float* bias   = (const float*)d_in[3];   // 1
    float* out = (float*)d_out;                    // 32*64*128 fp32
    float* y   = (float*)d_ws;                     // 2 MiB scratch

    chan_reduce<<<dim3(512), dim3(256), 0, stream>>>(x, w, y);
    radon_k<<<dim3(B_ * 16), dim3(512), 0, stream>>>(y, angles, bias, out);
}